// Round 1
// 285.890 us; speedup vs baseline: 1.0003x; 1.0003x over previous
//
#include <hip/hip_runtime.h>
#include <hip/hip_bf16.h>
#include <hip/hip_fp16.h>
#include <math.h>
#include <string.h>

// Problem constants (from reference)
#define BINSIZE 200
#define BINW 500          // WIDTH / BINSIZE
#define NCLUST 20
#define NREG_OI 200
#define LOG_BINSIZE   5.2983173665480363f   // log(200)
#define LOG_BINWIDTH  6.2146080984221914f   // log(500)
#define LOG_OUTWIDTH 11.5079131920500050f   // log(100000 - 500)

// Native Clang vector types — required by __builtin_nontemporal_load/store
typedef int   vint2   __attribute__((ext_vector_type(2)));
typedef int   vint4   __attribute__((ext_vector_type(4)));
typedef float vfloat4 __attribute__((ext_vector_type(4)));

// ---------------------------------------------------------------------------
// Phase 1: heights[r, c, b] = log_softmax_b(baseline[g,b] + delta[g,c,b]) - log(200)
// Stored as f16: 200*20*500*2 = 4 MB -> fits per-XCD L2.
// One wave per (r, c) row of 500 bins; 4 waves per 256-thread block.
// ---------------------------------------------------------------------------
__global__ void heights_kernel(const float* __restrict__ baseline,   // [5000, 500]
                               const float* __restrict__ delta,      // [5000, 20, 500]
                               const int*   __restrict__ regions_oi, // [200]
                               _Float16*    __restrict__ heights)    // [200, 20, 500] (ws)
{
    const int wave = blockIdx.x * 4 + (threadIdx.x >> 6);
    const int lane = threadIdx.x & 63;
    if (wave >= NREG_OI * NCLUST) return;

    const int r = wave / NCLUST;
    const int c = wave % NCLUST;
    const int g = regions_oi[r];

    const float* bptr = baseline + (size_t)g * BINW;
    const float* dptr = delta + ((size_t)g * NCLUST + c) * BINW;

    float u[8];
    float m = -INFINITY;
#pragma unroll
    for (int k = 0; k < 8; ++k) {
        const int b = lane + 64 * k;
        // delta rows are read exactly once across the whole grid -> non-temporal
        u[k] = (b < BINW)
             ? (bptr[b] + __builtin_nontemporal_load(dptr + b))
             : -INFINITY;
        m = fmaxf(m, u[k]);
    }
#pragma unroll
    for (int off = 32; off > 0; off >>= 1)
        m = fmaxf(m, __shfl_xor(m, off));

    float s = 0.f;
#pragma unroll
    for (int k = 0; k < 8; ++k) {
        const int b = lane + 64 * k;
        if (b < BINW) s += __expf(u[k] - m);
    }
#pragma unroll
    for (int off = 32; off > 0; off >>= 1)
        s += __shfl_xor(s, off);

    const float lse = m + __logf(s);
    _Float16* hptr = heights + (size_t)wave * BINW;
#pragma unroll
    for (int k = 0; k < 8; ++k) {
        const int b = lane + 64 * k;
        if (b < BINW) hptr[b] = (_Float16)(u[k] - lse - LOG_BINSIZE);
    }
}

// ---------------------------------------------------------------------------
// Phase 2: FOUR fragments per thread — 2x dwordx4 coords, dwordx4 lrix,
// dwordx4 lcix, 2x dwordx4 store. Four independent labels->heights gather
// chains per thread for latency overlap (the chain is 2 dependent L2 trips).
// Streamed arrays are non-temporal so the 4 MB heights table + 400 KB labels
// table stay L2-hot.
// ---------------------------------------------------------------------------
__global__ __launch_bounds__(256)
void frag_kernel(const _Float16* __restrict__ heights, // [200, 20, 500]
                 const int*      __restrict__ coords,  // [N, 2]
                 const int*      __restrict__ lrix,    // [N]
                 const int*      __restrict__ lcix,    // [N]
                 const int*      __restrict__ labels,  // [100000]
                 const float*    __restrict__ inside,  // [1]
                 float*          __restrict__ out,     // [N, 2]
                 int N)                                // 2,000,000
{
    const int q  = blockIdx.x * blockDim.x + threadIdx.x;
    const int f0 = q * 4;
    if (f0 >= N) return;

    const float x  = inside[0];
    const float sg = 1.f / (1.f + __expf(-x));
    const float lp_in  = __logf(sg)       - LOG_BINWIDTH;
    const float lp_out = __logf(1.f - sg) - LOG_OUTWIDTH;

    if (f0 + 3 < N) {
        // 4 fragments: 16B+16B coords, 16B region idx, 16B cell idx
        const vint4 c01 = __builtin_nontemporal_load((const vint4*)coords + 2 * q);
        const vint4 c23 = __builtin_nontemporal_load((const vint4*)coords + 2 * q + 1);
        const vint4 rr  = __builtin_nontemporal_load((const vint4*)lrix + q);
        const vint4 ce  = __builtin_nontemporal_load((const vint4*)lcix + q);

        // four independent gather chains (labels table 400 KB, L2-hot)
        const int lab0 = labels[ce.x];
        const int lab1 = labels[ce.y];
        const int lab2 = labels[ce.z];
        const int lab3 = labels[ce.w];

        const unsigned bl0 = (unsigned)c01.x / (unsigned)BINSIZE;
        const unsigned br0 = (unsigned)c01.y / (unsigned)BINSIZE;
        const unsigned bl1 = (unsigned)c01.z / (unsigned)BINSIZE;
        const unsigned br1 = (unsigned)c01.w / (unsigned)BINSIZE;
        const unsigned bl2 = (unsigned)c23.x / (unsigned)BINSIZE;
        const unsigned br2 = (unsigned)c23.y / (unsigned)BINSIZE;
        const unsigned bl3 = (unsigned)c23.z / (unsigned)BINSIZE;
        const unsigned br3 = (unsigned)c23.w / (unsigned)BINSIZE;

        const float h0 = (float)heights[((size_t)rr.x * NCLUST + lab0) * BINW + bl0];
        const float h1 = (float)heights[((size_t)rr.y * NCLUST + lab1) * BINW + bl1];
        const float h2 = (float)heights[((size_t)rr.z * NCLUST + lab2) * BINW + bl2];
        const float h3 = (float)heights[((size_t)rr.w * NCLUST + lab3) * BINW + bl3];

        vfloat4 o01, o23;
        o01.x = h0;
        o01.y = (bl0 == br0) ? lp_in : lp_out;
        o01.z = h1;
        o01.w = (bl1 == br1) ? lp_in : lp_out;
        o23.x = h2;
        o23.y = (bl2 == br2) ? lp_in : lp_out;
        o23.z = h3;
        o23.w = (bl3 == br3) ? lp_in : lp_out;
        __builtin_nontemporal_store(o01, (vfloat4*)out + 2 * q);
        __builtin_nontemporal_store(o23, (vfloat4*)out + 2 * q + 1);
    } else {
        // scalar tail (never taken for N = 2,000,000; kept for robustness)
        for (int f = f0; f < N; ++f) {
            const unsigned bl = (unsigned)coords[2 * f]     / (unsigned)BINSIZE;
            const unsigned br = (unsigned)coords[2 * f + 1] / (unsigned)BINSIZE;
            const int lab = labels[lcix[f]];
            const float h = (float)heights[((size_t)lrix[f] * NCLUST + lab) * BINW + bl];
            out[2 * f]     = h;
            out[2 * f + 1] = (bl == br) ? lp_in : lp_out;
        }
    }
}

// ---------------------------------------------------------------------------
extern "C" void kernel_launch(void* const* d_in, const int* in_sizes, int n_in,
                              void* d_out, int out_size, void* d_ws, size_t ws_size,
                              hipStream_t stream) {
    const float* baseline   = (const float*)d_in[0];
    const float* delta      = (const float*)d_in[1];
    const float* inside     = (const float*)d_in[2];
    const int*   regions_oi = (const int*)d_in[3];
    const int*   coords     = (const int*)d_in[4];
    const int*   lrix       = (const int*)d_in[5];
    const int*   lcix       = (const int*)d_in[6];
    const int*   labels     = (const int*)d_in[7];
    float*       out        = (float*)d_out;
    _Float16*    heights    = (_Float16*)d_ws;   // 200*20*500*2 = 4 MB

    const int N     = in_sizes[4] / 2;           // 2,000,000 fragments
    const int Nquad = (N + 3) / 4;

    heights_kernel<<<(NREG_OI * NCLUST + 3) / 4, 256, 0, stream>>>(
        baseline, delta, regions_oi, heights);

    frag_kernel<<<(Nquad + 255) / 256, 256, 0, stream>>>(
        heights, coords, lrix, lcix, labels, inside, out, N);
}